// Round 8
// baseline (471.038 us; speedup 1.0000x reference)
//
#include <hip/hip_runtime.h>
#include <math.h>

#define N_NODES 5000
#define N_EDGES 50000
#define NPAD 5008                 // 313 * 16
#define KP 4224                   // 66 k-slots of 64 = 33 chunks of 128
#define NCH 33

typedef _Float16 f16x8 __attribute__((ext_vector_type(8)));
typedef float    f32x4 __attribute__((ext_vector_type(4)));

static __device__ __forceinline__ f32x4 mfma16f(f16x8 a, f16x8 b, f32x4 c) {
    return __builtin_amdgcn_mfma_f32_16x16x32_f16(a, b, c, 0, 0, 0);
}

// ---------------- prep_misc: h16 convert (+pad rows) | Bh pack | cnt zero --
__global__ void prep_misc(const float* __restrict__ h, const float* __restrict__ Whh,
                          _Float16* __restrict__ h16, _Float16* __restrict__ Bh,
                          int* __restrict__ cnt) {
    int g = blockIdx.x * 256 + threadIdx.x;
    if (g < 320512) {                      // h16, rows >=5000 zero-padded
        h16[g] = (g < 320000) ? (_Float16)h[g] : (_Float16)0.f;
        return;
    }
    g -= 320512;
    if (g < 1536) {                        // Bh: Whh in MFMA B-fragment order
        int nt = g >> 7, ksl = (g >> 6) & 1, lane = g & 63;
        int lo = lane & 15, q = lane >> 4;
        int r = nt * 16 + lo, j0 = ksl * 32 + q * 8;
        f16x8 v;
#pragma unroll
        for (int p = 0; p < 8; ++p) v[p] = (_Float16)Whh[r * 64 + j0 + p];
        *(f16x8*)(Bh + (size_t)g * 8) = v;
        return;
    }
    g -= 1536;
    if (g < N_NODES) cnt[g] = 0;
}

// ---------------- wg_pack: Wg = Wih @ Wr, packed to B-fragment layout ------
// Wr[i][kappa=k*64+j] = W2[k*4096+i*64+j] (k<64) | b2[i*64+j] (k==64) | 0
// block = kappa-chunk c of 64 (c = k slot, 0..65); Bg[((nt*132+ks)*64+lane)*8+p]
__global__ __launch_bounds__(256) void wg_pack(const float* __restrict__ W2,
                                               const float* __restrict__ b2,
                                               const float* __restrict__ Wih,
                                               _Float16* __restrict__ Bg) {
    __shared__ float wsm[4096];            // Wr[i=0..63][u=0..63] for this slot
    int tid = threadIdx.x, c = blockIdx.x;
#pragma unroll
    for (int it = 0; it < 16; ++it) {
        int idx = it * 256 + tid;
        float v = 0.f;
        if (c < 64) v = W2[(size_t)c * 4096 + idx];
        else if (c == 64) v = b2[idx];
        wsm[idx] = v;
    }
    __syncthreads();
    for (int rep = 0; rep < 6; ++rep) {
        int o = rep * 256 + tid;           // 1536 f16x8 outputs per chunk
        int nt = o >> 7, ksl = (o >> 6) & 1, lane = o & 63;
        int lo = lane & 15, q = lane >> 4;
        int r = nt * 16 + lo, u0 = ksl * 32 + q * 8;
        float acc[8] = {0, 0, 0, 0, 0, 0, 0, 0};
        for (int i = 0; i < 64; ++i) {
            float wv = Wih[r * 64 + i];
            const float* wp = wsm + i * 64 + u0;
#pragma unroll
            for (int p = 0; p < 8; ++p) acc[p] += wv * wp[p];
        }
        f16x8 v;
#pragma unroll
        for (int p = 0; p < 8; ++p) v[p] = (_Float16)acc[p];
        *(f16x8*)(Bg + ((size_t)((nt * 132 + (c * 2 + ksl)) * 64 + lane)) * 8) = v;
    }
}

// ---------------- counting sort of edges by TGT ----------------------------
__global__ void hist_kernel(const int* __restrict__ ei, int* __restrict__ cnt) {
    int e = blockIdx.x * 256 + threadIdx.x;
    if (e < N_EDGES) atomicAdd(&cnt[ei[N_EDGES + e]], 1);
}

__global__ __launch_bounds__(1024) void scan_kernel(const int* __restrict__ cnt,
                                                    int* __restrict__ off,
                                                    int* __restrict__ cur) {
    __shared__ int s[1024];
    int tid = threadIdx.x;
    int base = tid * 5;
    int loc[5]; int sum = 0;
#pragma unroll
    for (int q = 0; q < 5; ++q) {
        int v = (base + q < N_NODES) ? cnt[base + q] : 0;
        loc[q] = sum; sum += v;
    }
    s[tid] = sum; __syncthreads();
    for (int d = 1; d < 1024; d <<= 1) {
        int v = (tid >= d) ? s[tid - d] : 0;
        __syncthreads();
        s[tid] += v;
        __syncthreads();
    }
    int excl = (tid > 0) ? s[tid - 1] : 0;
#pragma unroll
    for (int q = 0; q < 5; ++q)
        if (base + q < N_NODES) { off[base + q] = excl + loc[q]; cur[base + q] = excl + loc[q]; }
    if (tid == 1023) off[N_NODES] = excl + sum;
}

__global__ void scatter_kernel(const int* __restrict__ ei, int* __restrict__ cur,
                               int* __restrict__ srcp, int* __restrict__ eidp) {
    int e = blockIdx.x * 256 + threadIdx.x;
    if (e < N_EDGES) {
        int q = atomicAdd(&cur[ei[N_EDGES + e]], 1);
        srcp[q] = ei[e];
        eidp[q] = e;
    }
}

// ---------------- t[q] = relu(ef[eidp[q]] @ W1 + b1) (tgt-sorted order) ----
__global__ void edge_mlp1_kernel(const int* __restrict__ eidp,
                                 const float* __restrict__ ef,
                                 const float* __restrict__ W1,
                                 const float* __restrict__ b1,
                                 float* __restrict__ t) {
    int gid = blockIdx.x * 256 + threadIdx.x;   // exact: 12500*256 = E*64
    int q = gid >> 6, i = gid & 63;
    int e = eidp[q];
    float acc = b1[i];
#pragma unroll
    for (int k = 0; k < 16; ++k)
        acc += ef[e * 16 + k] * W1[k * 64 + i];
    t[gid] = fmaxf(acc, 0.f);
}

// ---------------- H[v][k*64+j] = sum_{e->v} t[e,k]*h[src,j]; slot64 = sum h
__global__ __launch_bounds__(256) void hbuild_kernel(const int* __restrict__ toff,
                                                     const int* __restrict__ srcp,
                                                     const float* __restrict__ t,
                                                     const float* __restrict__ h,
                                                     _Float16* __restrict__ H) {
    int wave = threadIdx.x >> 6, lane = threadIdx.x & 63;
    int v = blockIdx.x * 4 + wave;                // grid 1252 -> 5008
    float acc[65];
#pragma unroll
    for (int k = 0; k < 65; ++k) acc[k] = 0.f;
    if (v < N_NODES) {
        int s0 = toff[v], s1 = toff[v + 1];
        if (s0 < s1) {
            float hv_next = h[srcp[s0] * 64 + lane];     // pipelined h gather
            for (int q = s0; q < s1; ++q) {
                float hv = hv_next;
                if (q + 1 < s1) hv_next = h[srcp[q + 1] * 64 + lane];
                const float4* tq = (const float4*)(t + (size_t)q * 64);
#pragma unroll
                for (int kb = 0; kb < 16; ++kb) {
                    float4 tv = tq[kb];                  // uniform -> s_load
                    acc[kb * 4 + 0] += tv.x * hv;
                    acc[kb * 4 + 1] += tv.y * hv;
                    acc[kb * 4 + 2] += tv.z * hv;
                    acc[kb * 4 + 3] += tv.w * hv;
                }
                acc[64] += hv;
            }
        }
    }
    _Float16* Hv = H + (size_t)v * KP + lane;
#pragma unroll
    for (int k = 0; k < 65; ++k) Hv[k * 64] = (_Float16)acc[k];
    Hv[65 * 64] = (_Float16)0.f;                  // pad slot
}

// ---------------- fused: [gi|gh](5008x384) via MFMA + GRU elementwise ------
// 313 blocks x 256 thr. A (H rows) LDS-staged dbuf; B pre-packed coalesced.
__global__ __launch_bounds__(256) void gemm_gru(const _Float16* __restrict__ H,
                                                const _Float16* __restrict__ Bg,
                                                const _Float16* __restrict__ Bh,
                                                const _Float16* __restrict__ h16,
                                                const float* __restrict__ h,
                                                const float* __restrict__ bih,
                                                const float* __restrict__ bhh,
                                                float* __restrict__ out) {
    __shared__ _Float16 As[2][16 * 144];          // A chunk 16 x 128, pad 144
    __shared__ float gbuf[16 * 384];              // [node][0..191 gi | 192.. gh]
    int tid = threadIdx.x, w = tid >> 6, lane = tid & 63;
    int lo = lane & 15, q = lane >> 4;
    int m0 = blockIdx.x * 16;
    int ar = tid >> 4, ac = (tid & 15) * 8;       // staging: row ar, col-seg ac
    const _Float16* Ag = H + (size_t)(m0 + ar) * KP + ac;
    f32x4 zero4 = {0.f, 0.f, 0.f, 0.f};
    f32x4 accg[6] = {zero4, zero4, zero4, zero4, zero4, zero4};
    f32x4 acch[3] = {zero4, zero4, zero4};
    // gh = h @ Whh^T : 2 k-steps, A direct from h16 (L2-hot)
#pragma unroll
    for (int ks2 = 0; ks2 < 2; ++ks2) {
        f16x8 a = *(const f16x8*)(h16 + (size_t)(m0 + lo) * 64 + ks2 * 32 + q * 8);
#pragma unroll
        for (int j = 0; j < 3; ++j) {
            f16x8 b = *(const f16x8*)(Bh + ((size_t)(((w + 4 * j) * 2 + ks2) * 64 + lane)) * 8);
            acch[j] = mfma16f(a, b, acch[j]);
        }
    }
    // gi = H @ Wg^T : 33 chunks of 128, LDS dbuf + depth-2 register prefetch
    f16x8 pf = *(const f16x8*)(Ag);
    *(f16x8*)(&As[0][0] + ar * 144 + ac) = pf;
    pf = *(const f16x8*)(Ag + 128);
    __syncthreads();
    for (int c = 0; c < NCH; ++c) {
        f16x8 nxt = pf;
        if (c + 2 < NCH) nxt = *(const f16x8*)(Ag + (size_t)(c + 2) * 128);
        const _Float16* Ar = &As[c & 1][0];
#pragma unroll
        for (int ks = 0; ks < 4; ++ks) {
            f16x8 a = *(const f16x8*)(Ar + lo * 144 + ks * 32 + q * 8);
            int ksg = c * 4 + ks;
#pragma unroll
            for (int j = 0; j < 6; ++j) {
                f16x8 b = *(const f16x8*)(Bg + ((size_t)(((w + 4 * j) * 132 + ksg) * 64 + lane)) * 8);
                accg[j] = mfma16f(a, b, accg[j]);
            }
        }
        if (c + 1 < NCH) *(f16x8*)(&As[(c + 1) & 1][0] + ar * 144 + ac) = pf;
        pf = nxt;
        __syncthreads();
    }
    int row4 = q * 4;
#pragma unroll
    for (int j = 0; j < 6; ++j) {                 // D: col=lane&15, row=quad*4+g
        int ntc = (w + 4 * j) * 16 + lo;
#pragma unroll
        for (int g = 0; g < 4; ++g) gbuf[(row4 + g) * 384 + ntc] = accg[j][g];
    }
#pragma unroll
    for (int j = 0; j < 3; ++j) {
        int ntc = (w + 4 * j) * 16 + lo + 192;
#pragma unroll
        for (int g = 0; g < 4; ++g) gbuf[(row4 + g) * 384 + ntc] = acch[j][g];
    }
    __syncthreads();
    int i = lane;
#pragma unroll
    for (int u = 0; u < 4; ++u) {
        int nl = w * 4 + u, n = m0 + nl;
        if (n >= N_NODES) continue;
        const float* gb = gbuf + nl * 384;
        float ir  = gb[i]       + bih[i];
        float iz  = gb[64 + i]  + bih[64 + i];
        float inn = gb[128 + i] + bih[128 + i];
        float hr  = gb[192 + i] + bhh[i];
        float hz  = gb[256 + i] + bhh[64 + i];
        float hn  = gb[320 + i] + bhh[128 + i];
        float hval = h[(size_t)n * 64 + i];
        float r = 1.f / (1.f + expf(-(ir + hr)));
        float z = 1.f / (1.f + expf(-(iz + hz)));
        float nn = tanhf(inn + r * hn);
        out[n * 64 + i] = (1.f - z) * nn + z * hval;
    }
}

extern "C" void kernel_launch(void* const* d_in, const int* in_sizes, int n_in,
                              void* d_out, int out_size, void* d_ws, size_t ws_size,
                              hipStream_t stream) {
    const float* h   = (const float*)d_in[0];
    const int*   ei  = (const int*)d_in[1];    // [2, E]: row0 = src, row1 = tgt
    const float* ef  = (const float*)d_in[2];
    const float* W1  = (const float*)d_in[3];
    const float* b1  = (const float*)d_in[4];
    const float* W2  = (const float*)d_in[5];
    const float* b2  = (const float*)d_in[6];
    const float* Wih = (const float*)d_in[7];
    const float* Whh = (const float*)d_in[8];
    const float* bih = (const float*)d_in[9];
    const float* bhh = (const float*)d_in[10];
    float* out = (float*)d_out;

    // ws (~58 MB): t | H | Bg | Bh | h16 | cnt | toff | cur | srcp | eidp
    float*    t    = (float*)d_ws;                         // 3,200,000 f32
    _Float16* H    = (_Float16*)(t + 3200000);             // NPAD*KP f16 (42.3 MB)
    _Float16* Bg   = H + (size_t)NPAD * KP;                // 811,008 f16
    _Float16* Bh   = Bg + 811008;                          // 12,288 f16
    _Float16* h16  = Bh + 12288;                           // 320,512 f16
    int*      cnt  = (int*)(h16 + 320512);                 // 5000
    int*      toff = cnt + N_NODES;                        // 5001
    int*      cur  = toff + N_NODES + 1;                   // 5000
    int*      srcp = cur + N_NODES;                        // 50000
    int*      eidp = srcp + N_EDGES;                       // 50000

    prep_misc<<<1278, 256, 0, stream>>>(h, Whh, h16, Bh, cnt);
    wg_pack<<<66, 256, 0, stream>>>(W2, b2, Wih, Bg);
    hist_kernel<<<196, 256, 0, stream>>>(ei, cnt);
    scan_kernel<<<1, 1024, 0, stream>>>(cnt, toff, cur);
    scatter_kernel<<<196, 256, 0, stream>>>(ei, cur, srcp, eidp);
    edge_mlp1_kernel<<<12500, 256, 0, stream>>>(eidp, ef, W1, b1, t);
    hbuild_kernel<<<1252, 256, 0, stream>>>(toff, srcp, t, h, H);
    gemm_gru<<<313, 256, 0, stream>>>(H, Bg, Bh, h16, h, bih, bhh, out);
}

// Round 9
// 218.743 us; speedup vs baseline: 2.1534x; 2.1534x over previous
//
#include <hip/hip_runtime.h>
#include <math.h>

#define N_NODES 5000
#define N_EDGES 50000
#define NPAD 5008                 // 313 * 16
#define KP 4224                   // 66 k-slots of 64 = 33 chunks of 128
#define KSPLIT 3                  // 3 x 11 chunks

typedef _Float16 f16x8 __attribute__((ext_vector_type(8)));
typedef float    f32x4 __attribute__((ext_vector_type(4)));

static __device__ __forceinline__ f32x4 mfma16f(f16x8 a, f16x8 b, f32x4 c) {
    return __builtin_amdgcn_mfma_f32_16x16x32_f16(a, b, c, 0, 0, 0);
}

// ---------------- prep: Br pack (B-fragment order) + GRU transposes + cnt --
// Wr[i][kap]: kap=k*64+j -> k<64: W2[k*4096+i*64+j]; k==64: b2[i*64+j]; k==65: 0
// Br[((nt*132+ks)*64+lane)*8+p] = Wr[nt*16+(lane&15)][ks*32+(lane>>4)*8+p]
__global__ void prep_kernel(const float* __restrict__ W2, const float* __restrict__ b2,
                            const float* __restrict__ Wih, const float* __restrict__ Whh,
                            _Float16* __restrict__ Br, float* __restrict__ WihT,
                            float* __restrict__ WhhT, int* __restrict__ cnt) {
    int g = blockIdx.x * 256 + threadIdx.x;
    if (g < 33792) {                       // 4 nt * 132 ks * 64 lanes
        int nt = g / 8448, rem = g - nt * 8448;
        int ks = rem >> 6, lane = rem & 63;
        int lo = lane & 15, q = lane >> 4;
        int i = nt * 16 + lo, kap0 = ks * 32 + q * 8;
        int k = kap0 >> 6, j0 = kap0 & 63;
        f16x8 v;
#pragma unroll
        for (int p = 0; p < 8; ++p) {
            float x = 0.f;
            if (k < 64) x = W2[(size_t)k * 4096 + i * 64 + j0 + p];
            else if (k == 64) x = b2[i * 64 + j0 + p];
            v[p] = (_Float16)x;
        }
        *(f16x8*)(Br + (size_t)g * 8) = v;
        return;
    }
    g -= 33792;
    if (g < 24576) {                      // GRU weight transposes WT[j][row]
        int which = g >= 12288;
        int tt = which ? g - 12288 : g;
        int row = tt >> 6, j = tt & 63;
        (which ? WhhT : WihT)[j * 192 + row] = (which ? Whh : Wih)[tt];
        return;
    }
    g -= 24576;
    if (g < N_NODES) cnt[g] = 0;
}

// ---------------- counting sort of edges by TGT ----------------------------
__global__ void hist_kernel(const int* __restrict__ ei, int* __restrict__ cnt) {
    int e = blockIdx.x * 256 + threadIdx.x;
    if (e < N_EDGES) atomicAdd(&cnt[ei[N_EDGES + e]], 1);
}

__global__ __launch_bounds__(1024) void scan_kernel(const int* __restrict__ cnt,
                                                    int* __restrict__ off,
                                                    int* __restrict__ cur) {
    __shared__ int s[1024];
    int tid = threadIdx.x;
    int base = tid * 5;
    int loc[5]; int sum = 0;
#pragma unroll
    for (int q = 0; q < 5; ++q) {
        int v = (base + q < N_NODES) ? cnt[base + q] : 0;
        loc[q] = sum; sum += v;
    }
    s[tid] = sum; __syncthreads();
    for (int d = 1; d < 1024; d <<= 1) {
        int v = (tid >= d) ? s[tid - d] : 0;
        __syncthreads();
        s[tid] += v;
        __syncthreads();
    }
    int excl = (tid > 0) ? s[tid - 1] : 0;
#pragma unroll
    for (int q = 0; q < 5; ++q)
        if (base + q < N_NODES) { off[base + q] = excl + loc[q]; cur[base + q] = excl + loc[q]; }
    if (tid == 1023) off[N_NODES] = excl + sum;
}

__global__ void scatter_kernel(const int* __restrict__ ei, int* __restrict__ cur,
                               int* __restrict__ srcp, int* __restrict__ eidp) {
    int e = blockIdx.x * 256 + threadIdx.x;
    if (e < N_EDGES) {
        int q = atomicAdd(&cur[ei[N_EDGES + e]], 1);
        srcp[q] = ei[e];
        eidp[q] = e;
    }
}

// ---------------- t[q] = relu(ef[eidp[q]] @ W1 + b1) (tgt-sorted order) ----
__global__ void edge_mlp1_kernel(const int* __restrict__ eidp,
                                 const float* __restrict__ ef,
                                 const float* __restrict__ W1,
                                 const float* __restrict__ b1,
                                 float* __restrict__ t) {
    int gid = blockIdx.x * 256 + threadIdx.x;   // exact: 12500*256 = E*64
    int q = gid >> 6, i = gid & 63;
    int e = eidp[q];
    float acc = b1[i];
#pragma unroll
    for (int k = 0; k < 16; ++k)
        acc += ef[e * 16 + k] * W1[k * 64 + i];
    t[gid] = fmaxf(acc, 0.f);
}

// ---------------- H[v][k*64+j] = sum_{e->v} t[e,k]*h[src,j]; slot64 = sum h
// wave per target v; lane = j; edge-unroll x2 (independent gather chains)
__global__ __launch_bounds__(256) void hbuild_kernel(const int* __restrict__ toff,
                                                     const int* __restrict__ srcp,
                                                     const float* __restrict__ t,
                                                     const float* __restrict__ h,
                                                     _Float16* __restrict__ H) {
    int wave = threadIdx.x >> 6, lane = threadIdx.x & 63;
    int v = blockIdx.x * 4 + wave;                // grid 1252 -> 5008
    float acc[65];
#pragma unroll
    for (int k = 0; k < 65; ++k) acc[k] = 0.f;
    if (v < N_NODES) {
        int s0 = toff[v], s1 = toff[v + 1];
        int q = s0;
        for (; q + 1 < s1; q += 2) {
            float hv0 = h[srcp[q] * 64 + lane];       // two independent chains
            float hv1 = h[srcp[q + 1] * 64 + lane];
            const float4* t0 = (const float4*)(t + (size_t)q * 64);
            const float4* t1 = (const float4*)(t + (size_t)(q + 1) * 64);
#pragma unroll
            for (int kb = 0; kb < 16; ++kb) {
                float4 a = t0[kb], b = t1[kb];        // uniform -> s_load
                acc[kb * 4 + 0] += a.x * hv0; acc[kb * 4 + 0] += b.x * hv1;
                acc[kb * 4 + 1] += a.y * hv0; acc[kb * 4 + 1] += b.y * hv1;
                acc[kb * 4 + 2] += a.z * hv0; acc[kb * 4 + 2] += b.z * hv1;
                acc[kb * 4 + 3] += a.w * hv0; acc[kb * 4 + 3] += b.w * hv1;
            }
            acc[64] += hv0 + hv1;
        }
        if (q < s1) {
            float hv = h[srcp[q] * 64 + lane];
            const float4* tq = (const float4*)(t + (size_t)q * 64);
#pragma unroll
            for (int kb = 0; kb < 16; ++kb) {
                float4 tv = tq[kb];
                acc[kb * 4 + 0] += tv.x * hv;
                acc[kb * 4 + 1] += tv.y * hv;
                acc[kb * 4 + 2] += tv.z * hv;
                acc[kb * 4 + 3] += tv.w * hv;
            }
            acc[64] += hv;
        }
    }
    _Float16* Hv = H + (size_t)v * KP + lane;
#pragma unroll
    for (int k = 0; k < 65; ++k) Hv[k * 64] = (_Float16)acc[k];
    Hv[65 * 64] = (_Float16)0.f;                  // pad slot
}

// ---------------- m = H @ Wr^T, split-K partials (no atomics) --------------
// grid (313, 3); block 256 thr / 4 waves; wave w = n-tile w (N=64).
// 11 chunks of 128 per K-split; A LDS double-buffered, 1 barrier/chunk.
__global__ __launch_bounds__(256) void gemm_part(const _Float16* __restrict__ H,
                                                 const _Float16* __restrict__ Br,
                                                 float* __restrict__ gp) {
    __shared__ _Float16 As[2][16 * 136];          // row pad 136 (272B, 16B-aligned)
    int tid = threadIdx.x, w = tid >> 6, lane = tid & 63;
    int lo = lane & 15, q = lane >> 4;
    int m0 = blockIdx.x * 16;
    int ksp = blockIdx.y;                         // 0..2
    int ar = tid >> 4, ac = (tid & 15) * 8;
    const _Float16* Ag = H + (size_t)(m0 + ar) * KP + ksp * 1408 + ac;
    f32x4 acc = {0.f, 0.f, 0.f, 0.f};
    f16x8 pf = *(const f16x8*)(Ag);               // stage chunk 0
    *(f16x8*)(&As[0][ar * 136 + ac]) = pf;
    __syncthreads();
    for (int c = 0; c < 11; ++c) {
        if (c + 1 < 11) pf = *(const f16x8*)(Ag + (size_t)(c + 1) * 128);
        const _Float16* Arow = &As[c & 1][lo * 136];
        int ksg = (ksp * 11 + c) * 4;
#pragma unroll
        for (int ks = 0; ks < 4; ++ks) {
            f16x8 a = *(const f16x8*)(Arow + ks * 32 + q * 8);
            f16x8 b = *(const f16x8*)(Br + ((size_t)((w * 132 + ksg + ks) * 64 + lane)) * 8);
            acc = mfma16f(a, b, acc);
        }
        if (c + 1 < 11) *(f16x8*)(&As[(c + 1) & 1][ar * 136 + ac]) = pf;
        __syncthreads();
    }
    float* gpo = gp + (size_t)ksp * NPAD * 64;
    int row4 = q * 4;
#pragma unroll
    for (int g = 0; g < 4; ++g)                   // D: col=lane&15, row=quad*4+g
        gpo[(size_t)(m0 + row4 + g) * 64 + w * 16 + lo] = acc[g];
}

// ---------------- GRU cell: m = sum of 3 partials; transposed weights ------
__global__ void gru_kernel(const float* __restrict__ gp,
                           const float* __restrict__ h,
                           const float* __restrict__ WihT,
                           const float* __restrict__ WhhT,
                           const float* __restrict__ bih,
                           const float* __restrict__ bhh,
                           float* __restrict__ out) {
    int w = threadIdx.x >> 6, lane = threadIdx.x & 63;
    int n = blockIdx.x * 4 + w;                   // exact: 1250*4 = N
    int i = lane;
    float ir = bih[i], iz = bih[64 + i], inn = bih[128 + i];
    float hr = bhh[i], hz = bhh[64 + i], hn = bhh[128 + i];
    const float4* g0 = (const float4*)(gp + (size_t)n * 64);
    const float4* g1 = (const float4*)(gp + (size_t)NPAD * 64 + (size_t)n * 64);
    const float4* g2 = (const float4*)(gp + (size_t)2 * NPAD * 64 + (size_t)n * 64);
    const float4* hnp = (const float4*)(h + (size_t)n * 64);
#pragma unroll 4
    for (int qb = 0; qb < 16; ++qb) {
        float4 a = g0[qb], b = g1[qb], c = g2[qb]; // uniform -> s_load
        float4 hv = hnp[qb];
        float mj[4] = {a.x + b.x + c.x, a.y + b.y + c.y,
                       a.z + b.z + c.z, a.w + b.w + c.w};
        float hj[4] = {hv.x, hv.y, hv.z, hv.w};
#pragma unroll
        for (int u = 0; u < 4; ++u) {
            int j = qb * 4 + u;
            const float* wi = WihT + j * 192;     // lane-coalesced rows
            const float* wh = WhhT + j * 192;
            ir  += mj[u] * wi[i];
            iz  += mj[u] * wi[64 + i];
            inn += mj[u] * wi[128 + i];
            hr  += hj[u] * wh[i];
            hz  += hj[u] * wh[64 + i];
            hn  += hj[u] * wh[128 + i];
        }
    }
    float hval = h[(size_t)n * 64 + i];
    float r = 1.f / (1.f + expf(-(ir + hr)));
    float z = 1.f / (1.f + expf(-(iz + hz)));
    float nn = tanhf(inn + r * hn);
    out[n * 64 + i] = (1.f - z) * nn + z * hval;
}

extern "C" void kernel_launch(void* const* d_in, const int* in_sizes, int n_in,
                              void* d_out, int out_size, void* d_ws, size_t ws_size,
                              hipStream_t stream) {
    const float* h   = (const float*)d_in[0];
    const int*   ei  = (const int*)d_in[1];    // [2, E]: row0 = src, row1 = tgt
    const float* ef  = (const float*)d_in[2];
    const float* W1  = (const float*)d_in[3];
    const float* b1  = (const float*)d_in[4];
    const float* W2  = (const float*)d_in[5];
    const float* b2  = (const float*)d_in[6];
    const float* Wih = (const float*)d_in[7];
    const float* Whh = (const float*)d_in[8];
    const float* bih = (const float*)d_in[9];
    const float* bhh = (const float*)d_in[10];
    float* out = (float*)d_out;

    // ws (~60 MB): t | H | Br | WihT | WhhT | gp(x3) | cnt | toff | cur | srcp | eidp
    float*    t    = (float*)d_ws;                         // 3,200,000 f32
    _Float16* H    = (_Float16*)(t + 3200000);             // NPAD*KP f16 (42.3 MB)
    _Float16* Br   = H + (size_t)NPAD * KP;                // 270,336 f16
    float*    WihT = (float*)(Br + 270336);                // 12,288
    float*    WhhT = WihT + 12288;                         // 12,288
    float*    gp   = WhhT + 12288;                         // 3*NPAD*64
    int*      cnt  = (int*)(gp + (size_t)3 * NPAD * 64);   // 5000
    int*      toff = cnt + N_NODES;                        // 5001
    int*      cur  = toff + N_NODES + 1;                   // 5000
    int*      srcp = cur + N_NODES;                        // 50000
    int*      eidp = srcp + N_EDGES;                       // 50000

    prep_kernel<<<248, 256, 0, stream>>>(W2, b2, Wih, Whh, Br, WihT, WhhT, cnt);
    hist_kernel<<<196, 256, 0, stream>>>(ei, cnt);
    scan_kernel<<<1, 1024, 0, stream>>>(cnt, toff, cur);
    scatter_kernel<<<196, 256, 0, stream>>>(ei, cur, srcp, eidp);
    edge_mlp1_kernel<<<12500, 256, 0, stream>>>(eidp, ef, W1, b1, t);
    hbuild_kernel<<<1252, 256, 0, stream>>>(toff, srcp, t, h, H);
    gemm_part<<<dim3(313, KSPLIT), 256, 0, stream>>>(H, Br, gp);
    gru_kernel<<<1250, 256, 0, stream>>>(gp, h, WihT, WhhT, bih, bhh, out);
}

// Round 10
// 178.371 us; speedup vs baseline: 2.6408x; 1.2263x over previous
//
#include <hip/hip_runtime.h>
#include <math.h>

#define N_NODES 5000
#define N_EDGES 50000
#define NPAD 5008                 // 313 * 16
#define KP 4224                   // 33 k2-chunks of 128 (kap' = k2*128 + j*2 + par)
#define KSPLIT 3                  // 3 x 11 chunks

typedef _Float16 f16x8 __attribute__((ext_vector_type(8)));
typedef _Float16 f16x2 __attribute__((ext_vector_type(2)));
typedef float    f32x4 __attribute__((ext_vector_type(4)));

static __device__ __forceinline__ f32x4 mfma16f(f16x8 a, f16x8 b, f32x4 c) {
    return __builtin_amdgcn_mfma_f32_16x16x32_f16(a, b, c, 0, 0, 0);
}

// ---------------- prep: Br pack (B-fragment order, kap' map) + WT + cnt ----
// kap' = k2*128 + j*2 + par, k = 2*k2+par:
//   k<64: W2[k*4096+i*64+j]; k==64: b2[i*64+j]; k==65: 0
__global__ void prep_kernel(const float* __restrict__ W2, const float* __restrict__ b2,
                            const float* __restrict__ Wih, const float* __restrict__ Whh,
                            _Float16* __restrict__ Br, float* __restrict__ WihT,
                            float* __restrict__ WhhT, int* __restrict__ cnt) {
    int g = blockIdx.x * 256 + threadIdx.x;
    if (g < 33792) {                       // 4 nt * 132 ks * 64 lanes
        int nt = g / 8448, rem = g - nt * 8448;
        int ks = rem >> 6, lane = rem & 63;
        int lo = lane & 15, q = lane >> 4;
        int i = nt * 16 + lo, kap0 = ks * 32 + q * 8;
        f16x8 v;
#pragma unroll
        for (int p = 0; p < 8; ++p) {
            int kap = kap0 + p;
            int k2 = kap >> 7, rem2 = kap & 127;
            int j = rem2 >> 1, k = k2 * 2 + (rem2 & 1);
            float x = 0.f;
            if (k < 64) x = W2[(size_t)k * 4096 + i * 64 + j];
            else if (k == 64) x = b2[i * 64 + j];
            v[p] = (_Float16)x;
        }
        *(f16x8*)(Br + (size_t)g * 8) = v;
        return;
    }
    g -= 33792;
    if (g < 24576) {                      // GRU weight transposes WT[j][row]
        int which = g >= 12288;
        int tt = which ? g - 12288 : g;
        int row = tt >> 6, j = tt & 63;
        (which ? WhhT : WihT)[j * 192 + row] = (which ? Whh : Wih)[tt];
        return;
    }
    g -= 24576;
    if (g < N_NODES) cnt[g] = 0;
}

// ---------------- counting sort of edges by TGT ----------------------------
__global__ void hist_kernel(const int* __restrict__ ei, int* __restrict__ cnt) {
    int e = blockIdx.x * 256 + threadIdx.x;
    if (e < N_EDGES) atomicAdd(&cnt[ei[N_EDGES + e]], 1);
}

__global__ __launch_bounds__(1024) void scan_kernel(const int* __restrict__ cnt,
                                                    int* __restrict__ off,
                                                    int* __restrict__ cur) {
    __shared__ int s[1024];
    int tid = threadIdx.x;
    int base = tid * 5;
    int loc[5]; int sum = 0;
#pragma unroll
    for (int q = 0; q < 5; ++q) {
        int v = (base + q < N_NODES) ? cnt[base + q] : 0;
        loc[q] = sum; sum += v;
    }
    s[tid] = sum; __syncthreads();
    for (int d = 1; d < 1024; d <<= 1) {
        int v = (tid >= d) ? s[tid - d] : 0;
        __syncthreads();
        s[tid] += v;
        __syncthreads();
    }
    int excl = (tid > 0) ? s[tid - 1] : 0;
#pragma unroll
    for (int q = 0; q < 5; ++q)
        if (base + q < N_NODES) { off[base + q] = excl + loc[q]; cur[base + q] = excl + loc[q]; }
    if (tid == 1023) off[N_NODES] = excl + sum;
}

__global__ void scatter_kernel(const int* __restrict__ ei, int* __restrict__ cur,
                               int* __restrict__ srcp, int* __restrict__ eidp) {
    int e = blockIdx.x * 256 + threadIdx.x;
    if (e < N_EDGES) {
        int q = atomicAdd(&cur[ei[N_EDGES + e]], 1);
        srcp[q] = ei[e];
        eidp[q] = e;
    }
}

// ---------------- t[q] = relu(ef[eidp[q]] @ W1 + b1) (tgt-sorted order) ----
__global__ void edge_mlp1_kernel(const int* __restrict__ eidp,
                                 const float* __restrict__ ef,
                                 const float* __restrict__ W1,
                                 const float* __restrict__ b1,
                                 float* __restrict__ t) {
    int gid = blockIdx.x * 256 + threadIdx.x;   // exact: 12500*256 = E*64
    int q = gid >> 6, i = gid & 63;
    int e = eidp[q];
    float acc = b1[i];
#pragma unroll
    for (int k = 0; k < 16; ++k)
        acc += ef[e * 16 + k] * W1[k * 64 + i];
    t[gid] = fmaxf(acc, 0.f);
}

// ---------------- H build, k-split over 4 waves: wave=(v, kc) --------------
// H[v][kap'], kap' = k2*128 + j*2 + par. Wave kc owns k = kc*16..kc*16+15;
// kc==3 also writes k2=32 = (ones-slot, pad). 16 accs/wave -> deep pipelining.
__global__ __launch_bounds__(256) void hbuild_kernel(const int* __restrict__ toff,
                                                     const int* __restrict__ srcp,
                                                     const float* __restrict__ t,
                                                     const float* __restrict__ h,
                                                     _Float16* __restrict__ H) {
    int kc = threadIdx.x >> 6, lane = threadIdx.x & 63;
    int v = blockIdx.x;                           // grid NPAD; pad rows -> zeros
    float acc[16];
#pragma unroll
    for (int k = 0; k < 16; ++k) acc[k] = 0.f;
    float acc64 = 0.f;
    if (v < N_NODES) {
        int s0 = toff[v], s1 = toff[v + 1];
        int q = s0;
        for (; q + 1 < s1; q += 2) {              // two independent chains
            int sA = srcp[q], sB = srcp[q + 1];
            float hv0 = h[sA * 64 + lane];
            float hv1 = h[sB * 64 + lane];
            const float4* t0 = (const float4*)(t + (size_t)q * 64 + kc * 16);
            const float4* t1 = (const float4*)(t + (size_t)(q + 1) * 64 + kc * 16);
#pragma unroll
            for (int b = 0; b < 4; ++b) {
                float4 a = t0[b], c = t1[b];      // uniform -> s_load (quarter row)
                acc[b * 4 + 0] += a.x * hv0; acc[b * 4 + 0] += c.x * hv1;
                acc[b * 4 + 1] += a.y * hv0; acc[b * 4 + 1] += c.y * hv1;
                acc[b * 4 + 2] += a.z * hv0; acc[b * 4 + 2] += c.z * hv1;
                acc[b * 4 + 3] += a.w * hv0; acc[b * 4 + 3] += c.w * hv1;
            }
            acc64 += hv0 + hv1;
        }
        if (q < s1) {
            float hv = h[srcp[q] * 64 + lane];
            const float4* t0 = (const float4*)(t + (size_t)q * 64 + kc * 16);
#pragma unroll
            for (int b = 0; b < 4; ++b) {
                float4 a = t0[b];
                acc[b * 4 + 0] += a.x * hv;
                acc[b * 4 + 1] += a.y * hv;
                acc[b * 4 + 2] += a.z * hv;
                acc[b * 4 + 3] += a.w * hv;
            }
            acc64 += hv;
        }
    }
    _Float16* Hv = H + (size_t)v * KP;
#pragma unroll
    for (int p = 0; p < 8; ++p) {                 // paired stores: 256B/wave-instr
        f16x2 pv = { (_Float16)acc[p * 2], (_Float16)acc[p * 2 + 1] };
        *(f16x2*)(Hv + (kc * 8 + p) * 128 + lane * 2) = pv;
    }
    if (kc == 3) {                                // ones-slot (k=64) + pad (k=65)
        f16x2 pv = { (_Float16)acc64, (_Float16)0.f };
        *(f16x2*)(Hv + 32 * 128 + lane * 2) = pv;
    }
}

// ---------------- m = H @ Wr^T, split-K partials (no atomics) --------------
__global__ __launch_bounds__(256) void gemm_part(const _Float16* __restrict__ H,
                                                 const _Float16* __restrict__ Br,
                                                 float* __restrict__ gp) {
    __shared__ _Float16 As[2][16 * 136];          // row pad 136 (272B, 16B-aligned)
    int tid = threadIdx.x, w = tid >> 6, lane = tid & 63;
    int lo = lane & 15, q = lane >> 4;
    int m0 = blockIdx.x * 16;
    int ksp = blockIdx.y;                         // 0..2
    int ar = tid >> 4, ac = (tid & 15) * 8;
    const _Float16* Ag = H + (size_t)(m0 + ar) * KP + ksp * 1408 + ac;
    f32x4 acc = {0.f, 0.f, 0.f, 0.f};
    f16x8 pf = *(const f16x8*)(Ag);               // stage chunk 0
    *(f16x8*)(&As[0][ar * 136 + ac]) = pf;
    __syncthreads();
    for (int c = 0; c < 11; ++c) {
        if (c + 1 < 11) pf = *(const f16x8*)(Ag + (size_t)(c + 1) * 128);
        const _Float16* Arow = &As[c & 1][lo * 136];
        int ksg = (ksp * 11 + c) * 4;
#pragma unroll
        for (int ks = 0; ks < 4; ++ks) {
            f16x8 a = *(const f16x8*)(Arow + ks * 32 + q * 8);
            f16x8 b = *(const f16x8*)(Br + ((size_t)((w * 132 + ksg + ks) * 64 + lane)) * 8);
            acc = mfma16f(a, b, acc);
        }
        if (c + 1 < 11) *(f16x8*)(&As[(c + 1) & 1][ar * 136 + ac]) = pf;
        __syncthreads();
    }
    float* gpo = gp + (size_t)ksp * NPAD * 64;
    int row4 = q * 4;
#pragma unroll
    for (int g = 0; g < 4; ++g)                   // D: col=lane&15, row=quad*4+g
        gpo[(size_t)(m0 + row4 + g) * 64 + w * 16 + lo] = acc[g];
}

// ---------------- GRU cell: m = sum of 3 partials; transposed weights ------
__global__ void gru_kernel(const float* __restrict__ gp,
                           const float* __restrict__ h,
                           const float* __restrict__ WihT,
                           const float* __restrict__ WhhT,
                           const float* __restrict__ bih,
                           const float* __restrict__ bhh,
                           float* __restrict__ out) {
    int w = threadIdx.x >> 6, lane = threadIdx.x & 63;
    int n = blockIdx.x * 4 + w;                   // exact: 1250*4 = N
    int i = lane;
    float ir = bih[i], iz = bih[64 + i], inn = bih[128 + i];
    float hr = bhh[i], hz = bhh[64 + i], hn = bhh[128 + i];
    const float4* g0 = (const float4*)(gp + (size_t)n * 64);
    const float4* g1 = (const float4*)(gp + (size_t)NPAD * 64 + (size_t)n * 64);
    const float4* g2 = (const float4*)(gp + (size_t)2 * NPAD * 64 + (size_t)n * 64);
    const float4* hnp = (const float4*)(h + (size_t)n * 64);
#pragma unroll 4
    for (int qb = 0; qb < 16; ++qb) {
        float4 a = g0[qb], b = g1[qb], c = g2[qb]; // uniform -> s_load
        float4 hv = hnp[qb];
        float mj[4] = {a.x + b.x + c.x, a.y + b.y + c.y,
                       a.z + b.z + c.z, a.w + b.w + c.w};
        float hj[4] = {hv.x, hv.y, hv.z, hv.w};
#pragma unroll
        for (int u = 0; u < 4; ++u) {
            int j = qb * 4 + u;
            const float* wi = WihT + j * 192;     // lane-coalesced rows
            const float* wh = WhhT + j * 192;
            ir  += mj[u] * wi[i];
            iz  += mj[u] * wi[64 + i];
            inn += mj[u] * wi[128 + i];
            hr  += hj[u] * wh[i];
            hz  += hj[u] * wh[64 + i];
            hn  += hj[u] * wh[128 + i];
        }
    }
    float hval = h[(size_t)n * 64 + i];
    float r = 1.f / (1.f + expf(-(ir + hr)));
    float z = 1.f / (1.f + expf(-(iz + hz)));
    float nn = tanhf(inn + r * hn);
    out[n * 64 + i] = (1.f - z) * nn + z * hval;
}

extern "C" void kernel_launch(void* const* d_in, const int* in_sizes, int n_in,
                              void* d_out, int out_size, void* d_ws, size_t ws_size,
                              hipStream_t stream) {
    const float* h   = (const float*)d_in[0];
    const int*   ei  = (const int*)d_in[1];    // [2, E]: row0 = src, row1 = tgt
    const float* ef  = (const float*)d_in[2];
    const float* W1  = (const float*)d_in[3];
    const float* b1  = (const float*)d_in[4];
    const float* W2  = (const float*)d_in[5];
    const float* b2  = (const float*)d_in[6];
    const float* Wih = (const float*)d_in[7];
    const float* Whh = (const float*)d_in[8];
    const float* bih = (const float*)d_in[9];
    const float* bhh = (const float*)d_in[10];
    float* out = (float*)d_out;

    // ws (~60 MB): t | H | Br | WihT | WhhT | gp(x3) | cnt | toff | cur | srcp | eidp
    float*    t    = (float*)d_ws;                         // 3,200,000 f32
    _Float16* H    = (_Float16*)(t + 3200000);             // NPAD*KP f16 (42.3 MB)
    _Float16* Br   = H + (size_t)NPAD * KP;                // 270,336 f16
    float*    WihT = (float*)(Br + 270336);                // 12,288
    float*    WhhT = WihT + 12288;                         // 12,288
    float*    gp   = WhhT + 12288;                         // 3*NPAD*64
    int*      cnt  = (int*)(gp + (size_t)3 * NPAD * 64);   // 5000
    int*      toff = cnt + N_NODES;                        // 5001
    int*      cur  = toff + N_NODES + 1;                   // 5000
    int*      srcp = cur + N_NODES;                        // 50000
    int*      eidp = srcp + N_EDGES;                       // 50000

    prep_kernel<<<248, 256, 0, stream>>>(W2, b2, Wih, Whh, Br, WihT, WhhT, cnt);
    hist_kernel<<<196, 256, 0, stream>>>(ei, cnt);
    scan_kernel<<<1, 1024, 0, stream>>>(cnt, toff, cur);
    scatter_kernel<<<196, 256, 0, stream>>>(ei, cur, srcp, eidp);
    edge_mlp1_kernel<<<12500, 256, 0, stream>>>(eidp, ef, W1, b1, t);
    hbuild_kernel<<<NPAD, 256, 0, stream>>>(toff, srcp, t, h, H);
    gemm_part<<<dim3(313, KSPLIT), 256, 0, stream>>>(H, Br, gp);
    gru_kernel<<<1250, 256, 0, stream>>>(gp, h, WihT, WhhT, bih, bhh, out);
}